// Round 4
// baseline (168.037 us; speedup 1.0000x reference)
//
#include <hip/hip_runtime.h>

#define BUCKET_MASK ((1u << 21) - 1u)
#define NBIN 32768   // 32^3 spatial bins, bin edge 0.48 (= 2 level-0 cells)

typedef float f4 __attribute__((ext_vector_type(4)));

__device__ __forceinline__ int bin_key(float px, float py, float pz) {
    const float inv = 1.0f / 0.48f;
    int bx = (int)floorf(px * inv);
    int by = (int)floorf(py * inv);
    int bz = (int)floorf(pz * inv);
    bx = min(max(bx, -16), 15) + 16;   // Gaussian pts: |p|<5 => |b|<11, clamp is safety only
    by = min(max(by, -16), 15) + 16;
    bz = min(max(bz, -16), 15) + 16;
    return bx | (by << 5) | (bz << 10);
}

__global__ __launch_bounds__(256) void zero_hist_kernel(unsigned* __restrict__ hist) {
    int i = blockIdx.x * 256 + threadIdx.x;
    if (i < NBIN) hist[i] = 0u;
}

__global__ __launch_bounds__(256) void hist_kernel(const float* __restrict__ pts,
                                                   unsigned* __restrict__ hist, int npts) {
    int n = blockIdx.x * 256 + threadIdx.x;
    if (n >= npts) return;
    atomicAdd(&hist[bin_key(pts[n*3], pts[n*3+1], pts[n*3+2])], 1u);
}

// Exclusive scan of 32768 counters in one 1024-thread block (32 items/thread).
__global__ __launch_bounds__(1024) void scan_kernel(const unsigned* __restrict__ hist,
                                                    unsigned* __restrict__ cursor) {
    __shared__ unsigned sums[1024];
    int t = threadIdx.x;
    unsigned local[32];
    unsigned s = 0;
    #pragma unroll
    for (int j = 0; j < 32; ++j) { local[j] = hist[t*32 + j]; s += local[j]; }
    sums[t] = s;
    __syncthreads();
    for (int off = 1; off < 1024; off <<= 1) {   // Hillis-Steele inclusive scan
        unsigned v = (t >= off) ? sums[t - off] : 0u;
        __syncthreads();
        sums[t] += v;
        __syncthreads();
    }
    unsigned base = (t > 0) ? sums[t - 1] : 0u;
    #pragma unroll
    for (int j = 0; j < 32; ++j) { cursor[t*32 + j] = base; base += local[j]; }
}

__global__ __launch_bounds__(256) void scatter_kernel(const float* __restrict__ pts,
        unsigned* __restrict__ cursor, unsigned* __restrict__ order,
        float* __restrict__ spts, int npts) {
    int n = blockIdx.x * 256 + threadIdx.x;
    if (n >= npts) return;
    float px = pts[n*3], py = pts[n*3+1], pz = pts[n*3+2];
    unsigned pos = atomicAdd(&cursor[bin_key(px, py, pz)], 1u);
    order[pos] = (unsigned)n;
    spts[pos*3] = px; spts[pos*3+1] = py; spts[pos*3+2] = pz;
}

// blockIdx.y = level. 8 lanes per point (one float4 of the 32-float row each).
// Points arrive in bin-sorted order -> a wave's 8 points share a small vertex
// neighborhood -> gathers hit L1/L2. XCD-chunked swizzle keeps each XCD's L2
// on a contiguous spatial slab.
__global__ __launch_bounds__(256) void gather_sorted_kernel(
    const float* __restrict__ spts, const unsigned* __restrict__ order,
    const float* __restrict__ feats0, const float* __restrict__ feats1,
    float* __restrict__ out, int npts)
{
    int level = blockIdx.y;
    int nwg = gridDim.x, bid = blockIdx.x;
    int swz = ((nwg & 7) == 0) ? ((bid & 7) * (nwg >> 3) + (bid >> 3)) : bid;
    int t = swz * 256 + threadIdx.x;
    int i = t >> 3;              // sorted position
    int chunk = t & 7;           // float4 index within the 32-float row
    if (i >= npts) return;

    unsigned n = order[i];       // original point index (output row)
    const float res = level ? 0.12f : 0.24f;
    const float* __restrict__ feats = level ? feats1 : feats0;

    float px = spts[i*3], py = spts[i*3+1], pz = spts[i*3+2];

    // IEEE f32 divide to exactly match jnp (pts / float32(res))
    float qx = px / res, qy = py / res, qz = pz / res;
    float bx = floorf(qx), by = floorf(qy), bz = floorf(qz);
    float fx = qx - bx, fy = qy - by, fz = qz - bz;

    int ix = (int)bx, iy = (int)by, iz = (int)bz;

    // uint32 hash: low 21 bits of mod-2^32 sum == int64 floored mod 2^21.
    unsigned hx0 = (unsigned)ix * 73856093u;
    unsigned hy0 = (unsigned)iy * 19349669u;
    unsigned hz0 = (unsigned)iz * 83492791u;
    unsigned hx1 = hx0 + 73856093u;
    unsigned hy1 = hy0 + 19349669u;
    unsigned hz1 = hz0 + 83492791u;

    float gx = 1.0f - fx, gy = 1.0f - fy, gz = 1.0f - fz;
    f4 acc = (f4)(0.0f);

    #pragma unroll
    for (int c = 0; c < 8; ++c) {
        unsigned h = ((c & 1) ? hx1 : hx0)
                   + ((c & 2) ? hy1 : hy0)
                   + ((c & 4) ? hz1 : hz0);
        unsigned vid = h & BUCKET_MASK;
        float w = ((c & 1) ? fx : gx) * ((c & 2) ? fy : gy) * ((c & 4) ? fz : gz);
        const f4 f = *reinterpret_cast<const f4*>(
            feats + (size_t)vid * 32u + (unsigned)chunk * 4u);
        acc += w * f;
    }

    f4* dst = reinterpret_cast<f4*>(
        out + (size_t)n * 64u + (unsigned)level * 32u + (unsigned)chunk * 4u);
    __builtin_nontemporal_store(acc, dst);
}

// Fallback (no workspace): direct, unsorted.
__global__ __launch_bounds__(256) void gather_direct_kernel(
    const float* __restrict__ pts,
    const float* __restrict__ feats0, const float* __restrict__ feats1,
    float* __restrict__ out, int npts)
{
    int level = blockIdx.y;
    int t = blockIdx.x * 256 + threadIdx.x;
    int n = t >> 3, chunk = t & 7;
    if (n >= npts) return;
    const float res = level ? 0.12f : 0.24f;
    const float* __restrict__ feats = level ? feats1 : feats0;
    float qx = pts[n*3] / res, qy = pts[n*3+1] / res, qz = pts[n*3+2] / res;
    float bx = floorf(qx), by = floorf(qy), bz = floorf(qz);
    float fx = qx - bx, fy = qy - by, fz = qz - bz;
    int ix = (int)bx, iy = (int)by, iz = (int)bz;
    unsigned hx0 = (unsigned)ix * 73856093u, hy0 = (unsigned)iy * 19349669u, hz0 = (unsigned)iz * 83492791u;
    unsigned hx1 = hx0 + 73856093u, hy1 = hy0 + 19349669u, hz1 = hz0 + 83492791u;
    float gx = 1.0f - fx, gy = 1.0f - fy, gz = 1.0f - fz;
    f4 acc = (f4)(0.0f);
    #pragma unroll
    for (int c = 0; c < 8; ++c) {
        unsigned h = ((c&1)?hx1:hx0) + ((c&2)?hy1:hy0) + ((c&4)?hz1:hz0);
        unsigned vid = h & BUCKET_MASK;
        float w = ((c&1)?fx:gx) * ((c&2)?fy:gy) * ((c&4)?fz:gz);
        const f4 f = *reinterpret_cast<const f4*>(feats + (size_t)vid*32u + (unsigned)chunk*4u);
        acc += w * f;
    }
    f4* dst = reinterpret_cast<f4*>(out + (size_t)n*64u + (unsigned)level*32u + (unsigned)chunk*4u);
    __builtin_nontemporal_store(acc, dst);
}

extern "C" void kernel_launch(void* const* d_in, const int* in_sizes, int n_in,
                              void* d_out, int out_size, void* d_ws, size_t ws_size,
                              hipStream_t stream) {
    const float* pts = (const float*)d_in[0];
    const float* f0  = (const float*)d_in[1];
    const float* f1  = (const float*)d_in[2];
    float* out = (float*)d_out;

    int npts = in_sizes[0] / 3;               // 262144
    long long threads = (long long)npts * 8;
    int gx = (int)((threads + 255) / 256);
    dim3 grid(gx, 2, 1);

    size_t need = (size_t)NBIN * 8 + (size_t)npts * 16 + 256;
    if (ws_size >= need) {
        char* w = (char*)d_ws;
        unsigned* hist   = (unsigned*)w;  w += (size_t)NBIN * 4;
        unsigned* cursor = (unsigned*)w;  w += (size_t)NBIN * 4;
        unsigned* order  = (unsigned*)w;  w += (size_t)npts * 4;
        float*    spts   = (float*)w;

        int pblocks = (npts + 255) / 256;
        zero_hist_kernel<<<(NBIN + 255) / 256, 256, 0, stream>>>(hist);
        hist_kernel<<<pblocks, 256, 0, stream>>>(pts, hist, npts);
        scan_kernel<<<1, 1024, 0, stream>>>(hist, cursor);
        scatter_kernel<<<pblocks, 256, 0, stream>>>(pts, cursor, order, spts, npts);
        gather_sorted_kernel<<<grid, 256, 0, stream>>>(spts, order, f0, f1, out, npts);
    } else {
        gather_direct_kernel<<<grid, 256, 0, stream>>>(pts, f0, f1, out, npts);
    }
}

// Round 5
// 40.405 us; speedup vs baseline: 4.1588x; 4.1588x over previous
//
#include <hip/hip_runtime.h>

#define BUCKET_MASK ((1u << 21) - 1u)

__global__ __launch_bounds__(256) void voxel_hash_kernel(
    const float* __restrict__ pts,
    const float* __restrict__ feats0,
    const float* __restrict__ feats1,
    float* __restrict__ out,
    int npts)
{
    int gid = blockIdx.x * 256 + threadIdx.x;
    int n   = gid >> 4;          // point index
    int sub = gid & 15;          // 0..15: which float4 of the 64-float output row
    if (n >= npts) return;

    int level = sub >> 3;        // 0 -> features0/res .24, 1 -> features1/res .12
    int chunk = sub & 7;         // float4 index within the 32-float feature row

    const float res = level ? 0.12f : 0.24f;
    const float* __restrict__ feats = level ? feats1 : feats0;

    // Load point (16 lanes broadcast same 3 floats from L1)
    float px = pts[n * 3 + 0];
    float py = pts[n * 3 + 1];
    float pz = pts[n * 3 + 2];

    // IEEE f32 divide to exactly match jnp (pts / float32(res))
    float qx = px / res, qy = py / res, qz = pz / res;
    float bx = floorf(qx), by = floorf(qy), bz = floorf(qz);
    float fx = qx - bx, fy = qy - by, fz = qz - bz;

    int ix = (int)bx, iy = (int)by, iz = (int)bz;

    // Hash in uint32: (x*P0 + y*P1 + z*P2) mod 2^21 == low-21-bits of mod-2^32 sum.
    unsigned hx0 = (unsigned)ix * 73856093u;
    unsigned hy0 = (unsigned)iy * 19349669u;
    unsigned hz0 = (unsigned)iz * 83492791u;
    unsigned hx1 = hx0 + 73856093u;
    unsigned hy1 = hy0 + 19349669u;
    unsigned hz1 = hz0 + 83492791u;

    float gx = 1.0f - fx, gy = 1.0f - fy, gz = 1.0f - fz;

    float4 acc = make_float4(0.0f, 0.0f, 0.0f, 0.0f);

    #pragma unroll
    for (int c = 0; c < 8; ++c) {
        unsigned h = ((c & 1) ? hx1 : hx0)
                   + ((c & 2) ? hy1 : hy0)
                   + ((c & 4) ? hz1 : hz0);
        unsigned vid = h & BUCKET_MASK;
        float w = ((c & 1) ? fx : gx) * ((c & 2) ? fy : gy) * ((c & 4) ? fz : gz);

        const float4 f = *reinterpret_cast<const float4*>(
            feats + (size_t)vid * 32u + (unsigned)chunk * 4u);
        acc.x += w * f.x;
        acc.y += w * f.y;
        acc.z += w * f.z;
        acc.w += w * f.w;
    }

    *reinterpret_cast<float4*>(out + (size_t)n * 64u + (unsigned)sub * 4u) = acc;
}

extern "C" void kernel_launch(void* const* d_in, const int* in_sizes, int n_in,
                              void* d_out, int out_size, void* d_ws, size_t ws_size,
                              hipStream_t stream) {
    const float* pts = (const float*)d_in[0];
    const float* f0  = (const float*)d_in[1];
    const float* f1  = (const float*)d_in[2];
    float* out = (float*)d_out;

    int npts = in_sizes[0] / 3;               // 262144
    long long threads = (long long)npts * 16; // 16 lanes per point
    int grid = (int)((threads + 255) / 256);

    voxel_hash_kernel<<<grid, 256, 0, stream>>>(pts, f0, f1, out, npts);
}